// Round 9
// baseline (1480.621 us; speedup 1.0000x reference)
//
#include <hip/hip_runtime.h>

#define BB 32
#define DIM 4096
#define NH 32
#define NKV 8
#define HD 128
#define KVLEN 4096
#define QKVC 6144  // DIM + 2*NKV*HD
#define GQ 4
#define QKV_SPLITS 32
#define WO_SPLITS 32
#define ASPLIT 2   // KV splits for k_attn (2048 keys each) -> 512 blocks, ALL resident
#define NT 32      // tiles per block (2048 / 64)

typedef const __attribute__((address_space(1))) char gas_char;
typedef __attribute__((address_space(3))) char las_char;
#define GLL16(GP, LP) __builtin_amdgcn_global_load_lds((gas_char*)(GP), (las_char*)(LP), 16, 0, 0)

// ---------------- kernel A: xqkv partials = x @ wqkv (K-split, partials) -------
// 16-deep weight pipeline: 16x256B per wave in flight (~60 VGPR, no spill).
__global__ __launch_bounds__(256, 4) void k_qkv(const float* __restrict__ x,
                                                const float* __restrict__ w,
                                                float* __restrict__ part) {
    int j  = blockIdx.x * 256 + threadIdx.x;          // column 0..6143 (24 blocks)
    int d0 = blockIdx.y * (DIM / QKV_SPLITS);         // 128 rows per split
    float acc[BB];
#pragma unroll
    for (int b = 0; b < BB; ++b) acc[b] = 0.f;
    for (int dd = d0; dd < d0 + DIM / QKV_SPLITS; dd += 16) {
        float wr[16];
#pragma unroll
        for (int k = 0; k < 16; ++k) wr[k] = w[(size_t)(dd + k) * QKVC + j];
#pragma unroll
        for (int b = 0; b < BB; ++b) {
            float4 xa = *(const float4*)&x[b * DIM + dd];      // wave-uniform
            float4 xb = *(const float4*)&x[b * DIM + dd + 4];
            float4 xc = *(const float4*)&x[b * DIM + dd + 8];
            float4 xd = *(const float4*)&x[b * DIM + dd + 12];
            float t = acc[b];
            t = fmaf(xa.x, wr[0],  t); t = fmaf(xa.y, wr[1],  t);
            t = fmaf(xa.z, wr[2],  t); t = fmaf(xa.w, wr[3],  t);
            t = fmaf(xb.x, wr[4],  t); t = fmaf(xb.y, wr[5],  t);
            t = fmaf(xb.z, wr[6],  t); t = fmaf(xb.w, wr[7],  t);
            t = fmaf(xc.x, wr[8],  t); t = fmaf(xc.y, wr[9],  t);
            t = fmaf(xc.z, wr[10], t); t = fmaf(xc.w, wr[11], t);
            t = fmaf(xd.x, wr[12], t); t = fmaf(xd.y, wr[13], t);
            t = fmaf(xd.z, wr[14], t); t = fmaf(xd.w, wr[15], t);
            acc[b] = t;
        }
    }
#pragma unroll
    for (int b = 0; b < BB; ++b)
        part[(size_t)blockIdx.y * (BB * QKVC) + (size_t)b * QKVC + j] = acc[b];
}

// ---------------- generic split reduction: dst = sum_p src[p] ------------------
__global__ __launch_bounds__(256) void k_red(const float* __restrict__ src,
                                             float* __restrict__ dst,
                                             int parts, int n4) {
    int i = blockIdx.x * 256 + threadIdx.x;
    if (i >= n4) return;
    const float4* s4 = (const float4*)src;
    float4 a = s4[i];
    for (int p = 1; p < parts; ++p) {
        float4 b = s4[(size_t)p * n4 + i];
        a.x += b.x; a.y += b.y; a.z += b.z; a.w += b.w;
    }
    ((float4*)dst)[i] = a;
}

// ---------------- kernel R: rotary for q,k -> scratch (NO cache writes) --------
__global__ __launch_bounds__(128) void k_rot(const float* __restrict__ xqkv,
                                             const float* __restrict__ rot,
                                             float* __restrict__ qws,
                                             float* __restrict__ kws) {
    int c  = blockIdx.x;    // 0..39: 0-31 q heads, 32-39 k heads
    int b  = blockIdx.y;    // batch
    int dp = threadIdx.x;   // 0..127 output dim
    const float* row = &xqkv[(size_t)b * QKVC + c * HD];
    float acc = 0.f;
#pragma unroll 4
    for (int d = 0; d < HD; ++d) acc = fmaf(row[d], rot[d * HD + dp], acc);
    if (c < 32) {
        qws[((size_t)b * NH + c) * HD + dp] = acc;
    } else {
        int kvh = c - 32;
        kws[((size_t)b * NKV + kvh) * HD + dp] = acc;
    }
}

// ---------------- kernel B: flash attention, async-pipelined (T3/T4) -----------
// r8 schedule widened to 512 threads (8 waves) -> 2 blocks/CU = 4 waves/SIMD
// (was 2): doubles latency coverage of the serial dot/softmax phases.
// Phase A: wave pair per head, each wave half the dims (serial chain halved),
// partials via LDS. Phase A2: softmax on waves 0-3. Phase B: 16 subs x 4 keys.
// GLL K staging XOR-swizzled, V 2-deep in regs (32 VGPR), counted vmcnt 9/8.
__global__ __launch_bounds__(512, 4) void k_attn(const float* __restrict__ ck,
                                                 const float* __restrict__ cv,
                                                 const float* __restrict__ qws,
                                                 const float* __restrict__ kws,
                                                 const float* __restrict__ xqkv,
                                                 const float* __restrict__ mask,
                                                 const int* __restrict__ curpos,
                                                 float* __restrict__ opart,
                                                 float2* __restrict__ stats) {
    __shared__ float Kl[2][64 * 128];   // 64 KB, linear (gll dest), XOR-swizzled
    __shared__ float mbuf[2][GQ * 64];  // 2 KB mask tiles
    __shared__ float ql[GQ][HD];        // 2 KB
    __shared__ float pA[GQ][2][64];     // 2 KB partial dots (head, dim-half, key)
    __shared__ float pl[GQ * 64];       // 1 KB probabilities
    __shared__ float rs[GQ];
    int bkv = blockIdx.x;               // 0..255
    int split = blockIdx.y;             // 0..1
    int b = bkv >> 3, kv = bkv & 7;
    int tid = threadIdx.x;
    int w8 = tid >> 6, lane = tid & 63;    // 8 waves
    int hq = w8 >> 1, hf = w8 & 1;         // phase A: head, dim-half
    int hf16 = hf * 16;
    int d4 = tid & 31, sub = tid >> 5;     // phase B: 16 subs x 4 keys
    int lrh = lane >> 5;                   // row half for staging
    int sbyte = (lane & 31) << 4;          // swizzle byte offset
    int pos = *curpos;
    int L = min((((pos + 1) + 31) >> 5) << 5, KVLEN);
    int l0 = split * (NT * 64);
    const float scale = 0.08838834764831845f;  // 1/sqrt(128)

    // q of all 4 heads -> LDS (flat; visible after prologue lgkm drain + bar1)
    ql[tid >> 7][tid & 127] = qws[((size_t)b * NH + kv * GQ) * HD + tid];

    // dot(q[head], k_new) for the `pos` row; head = w8 for waves 0-3 (A2 users)
    int hp = w8 & 3;
    float posdot = 0.f;
    {
        const float4* kwr = (const float4*)&kws[((size_t)b * NKV + kv) * HD];
        const float4* qr  = (const float4*)&qws[((size_t)b * NH + kv * GQ + hp) * HD];
#pragma unroll
        for (int i = 0; i < 32; ++i) {
            float4 a = kwr[i], c = qr[i];
            posdot += a.x * c.x + a.y * c.y + a.z * c.z + a.w * c.w;
        }
    }
    float4 vnew4 = *(const float4*)&xqkv[(size_t)b * QKVC + (size_t)(NH + NKV) * HD + kv * HD + d4 * 4];

    const char*   Ktile0 = (const char*)(ck + ((size_t)bkv * KVLEN + l0) * HD);
    const float4* Vt0    = (const float4*)(cv + ((size_t)bkv * KVLEN + l0) * HD);

#define STAGE_K(T, BUFI) do {                                                    \
        const char* kb_ = Ktile0 + (size_t)(T) * 32768;                          \
        _Pragma("unroll")                                                        \
        for (int i_ = 0; i_ < 4; ++i_) {                                         \
            int row_ = w8 * 8 + i_ * 2 + lrh;                                    \
            int col_ = sbyte ^ ((row_ & 31) << 4);                               \
            GLL16(kb_ + (size_t)row_ * 512 + col_, &Kl[BUFI][(w8 * 8 + i_ * 2) * 128]); \
        }                                                                        \
    } while (0)

#define STAGE_M(T, BUFI) do {                                                    \
        int hh_ = lane >> 4, kk_ = lane & 15;                                    \
        const float* mg_ = mask + (((size_t)(kv * GQ + hh_) * BB + b) * KVLEN    \
                                   + l0 + (T) * 64 + kk_ * 4);                   \
        GLL16(mg_, &mbuf[BUFI][0]);                                              \
    } while (0)

#define LOADV(T, VBUF) do {                                                      \
        _Pragma("unroll")                                                        \
        for (int i_ = 0; i_ < 4; ++i_)                                           \
            (VBUF)[i_] = Vt0[(size_t)((T) * 64 + sub * 4 + i_) * 32 + d4];       \
    } while (0)

    float m = -3.0e38f, lsum = 0.f;
    float4 acc[GQ];
#pragma unroll
    for (int gg = 0; gg < GQ; ++gg) acc[gg] = make_float4(0.f, 0.f, 0.f, 0.f);
    float4 vA[4], vB[4];

    // prologue: tile 0 in flight; drain LDS writes (ql) before first barrier
    STAGE_K(0, 0);
    if (w8 == 0) STAGE_M(0, 0);
    LOADV(0, vA);
    asm volatile("s_waitcnt lgkmcnt(0)" ::: "memory");

#define TILE(T, BUFI, VC, VN) do {                                               \
        if ((T) < NT - 1) {                                                      \
            STAGE_K((T) + 1, (BUFI) ^ 1);                                        \
            if (w8 == 0) STAGE_M((T) + 1, (BUFI) ^ 1);                           \
            LOADV((T) + 1, VN);                                                  \
            if (w8 == 0) asm volatile("s_waitcnt vmcnt(9)" ::: "memory");        \
            else         asm volatile("s_waitcnt vmcnt(8)" ::: "memory");        \
        } else {                                                                 \
            asm volatile("s_waitcnt vmcnt(0)" ::: "memory");                     \
        }                                                                        \
        __builtin_amdgcn_s_barrier();   /* bar1: K(T) staged */                  \
        /* phase A: half-dot (64 dims) per wave, lane = key */                   \
        int lk_ = l0 + (T) * 64 + lane;                                          \
        const char* klr_ = (const char*)&Kl[BUFI][0] + lane * 512;               \
        float pd_ = 0.f;                                                         \
        _Pragma("unroll")                                                        \
        for (int j_ = 0; j_ < 16; ++j_) {                                        \
            int dd_ = hf16 + j_;                                                 \
            float4 kk4_ = *(const float4*)(klr_ + ((dd_ * 16) ^ sbyte));         \
            float4 qq4_ = *(const float4*)&ql[hq][dd_ * 4];                      \
            pd_ += kk4_.x * qq4_.x + kk4_.y * qq4_.y                             \
                 + kk4_.z * qq4_.z + kk4_.w * qq4_.w;                            \
        }                                                                        \
        pA[hq][hf][lane] = pd_;                                                  \
        asm volatile("s_waitcnt lgkmcnt(0)" ::: "memory");                       \
        __builtin_amdgcn_s_barrier();   /* bar2: partials ready */               \
        /* phase A2: combine + online softmax (waves 0-3, head = w8) */          \
        if (w8 < 4) {                                                            \
            float sdot_ = pA[w8][0][lane] + pA[w8][1][lane];                     \
            if (lk_ == pos) sdot_ = posdot;                                      \
            float s_ = sdot_ * scale + mbuf[BUFI][w8 * 64 + lane];               \
            if (lk_ >= L) s_ = -3.0e38f;                                         \
            float smax_ = s_;                                                    \
            _Pragma("unroll")                                                    \
            for (int off_ = 32; off_ > 0; off_ >>= 1)                            \
                smax_ = fmaxf(smax_, __shfl_xor(smax_, off_));                   \
            float mnew_ = fmaxf(m, smax_);                                       \
            float r_ = __expf(m - mnew_);                                        \
            float e_ = (lk_ < L) ? __expf(s_ - mnew_) : 0.f;                     \
            float esum_ = e_;                                                    \
            _Pragma("unroll")                                                    \
            for (int off_ = 32; off_ > 0; off_ >>= 1)                            \
                esum_ += __shfl_xor(esum_, off_);                                \
            lsum = lsum * r_ + esum_;                                            \
            m = mnew_;                                                           \
            pl[w8 * 64 + lane] = e_;                                             \
            if (lane == 0) rs[w8] = r_;                                          \
        }                                                                        \
        asm volatile("s_waitcnt lgkmcnt(0)" ::: "memory");                       \
        __builtin_amdgcn_s_barrier();   /* bar3: p, rs ready */                  \
        /* phase B: FMA from V regs, p via LDS broadcast */                      \
        int prow_ = pos - (l0 + (T) * 64);                                       \
        _Pragma("unroll")                                                        \
        for (int gg_ = 0; gg_ < GQ; ++gg_) {                                     \
            float rg_ = rs[gg_];                                                 \
            acc[gg_].x *= rg_; acc[gg_].y *= rg_;                                \
            acc[gg_].z *= rg_; acc[gg_].w *= rg_;                                \
        }                                                                        \
        _Pragma("unroll")                                                        \
        for (int i_ = 0; i_ < 4; ++i_) {                                         \
            float4 v_ = (sub * 4 + i_ == prow_) ? vnew4 : (VC)[i_];              \
            _Pragma("unroll")                                                    \
            for (int gg_ = 0; gg_ < GQ; ++gg_) {                                 \
                float p_ = pl[gg_ * 64 + sub * 4 + i_];                          \
                acc[gg_].x = fmaf(p_, v_.x, acc[gg_].x);                         \
                acc[gg_].y = fmaf(p_, v_.y, acc[gg_].y);                         \
                acc[gg_].z = fmaf(p_, v_.z, acc[gg_].z);                         \
                acc[gg_].w = fmaf(p_, v_.w, acc[gg_].w);                         \
            }                                                                    \
        }                                                                        \
    } while (0)

    for (int tt = 0; tt < NT; tt += 2) {
        TILE(tt,     0, vA, vB);
        TILE(tt + 1, 1, vB, vA);
    }

    if (w8 < 4 && lane == 0)
        stats[(bkv * GQ + w8) * ASPLIT + split] = make_float2(m, lsum);

    // cross-sub reduce of O partials (alias Kl as scratch; pipeline done)
    __syncthreads();
    float* red = &Kl[0][0];   // 16*4*128 floats = 32 KB < 64 KB
#pragma unroll
    for (int gg = 0; gg < GQ; ++gg)
        *(float4*)&red[(sub * GQ + gg) * HD + d4 * 4] = acc[gg];
    __syncthreads();
    {
        int g2 = tid >> 7, d = tid & 127;      // 512 threads = (g,d)
        float o = 0.f;
#pragma unroll
        for (int k = 0; k < 16; ++k) o += red[(k * GQ + g2) * HD + d];
        opart[(((size_t)split * 256 + bkv) * GQ + g2) * HD + d] = o;
    }
#undef TILE
#undef LOADV
#undef STAGE_K
#undef STAGE_M
}

// ---------------- kernel M: merge ASPLIT split partials -> attn ----------------
__global__ __launch_bounds__(128) void k_merge(const float* __restrict__ opart,
                                               const float2* __restrict__ stats,
                                               float* __restrict__ attn) {
    int bkv = blockIdx.x;    // 0..255
    int d = threadIdx.x;     // 0..127
    int b = bkv >> 3, kv = bkv & 7;
#pragma unroll
    for (int g = 0; g < GQ; ++g) {
        float2 st[ASPLIT];
        float M = -3.0e38f;
#pragma unroll
        for (int s = 0; s < ASPLIT; ++s) {
            st[s] = stats[(bkv * GQ + g) * ASPLIT + s];
            M = fmaxf(M, st[s].x);
        }
        float Ltot = 0.f;
        float w[ASPLIT];
#pragma unroll
        for (int s = 0; s < ASPLIT; ++s) {
            w[s] = __expf(st[s].x - M);
            Ltot += st[s].y * w[s];
        }
        float inv = Ltot > 0.f ? 1.f / Ltot : 0.f;
        float o = 0.f;
#pragma unroll
        for (int s = 0; s < ASPLIT; ++s)
            o += opart[(((size_t)s * 256 + bkv) * GQ + g) * HD + d] * (w[s] * inv);
        attn[(size_t)b * DIM + (kv * GQ + g) * HD + d] = o;
    }
}

// ---------------- kernel C: out partials = attn @ wo (K-split, partials) -------
__global__ __launch_bounds__(256, 4) void k_wo(const float* __restrict__ attn,
                                               const float* __restrict__ wo,
                                               float* __restrict__ part) {
    int j  = blockIdx.x * 256 + threadIdx.x;       // 0..4095 (16 blocks)
    int d0 = blockIdx.y * (DIM / WO_SPLITS);       // 128 rows per split
    float acc[BB];
#pragma unroll
    for (int b = 0; b < BB; ++b) acc[b] = 0.f;
    for (int dd = d0; dd < d0 + DIM / WO_SPLITS; dd += 8) {
        float wr[8];
#pragma unroll
        for (int k = 0; k < 8; ++k) wr[k] = wo[(size_t)(dd + k) * DIM + j];
#pragma unroll
        for (int b = 0; b < BB; ++b) {
            float4 xa = *(const float4*)&attn[b * DIM + dd];   // wave-uniform
            float4 xb = *(const float4*)&attn[b * DIM + dd + 4];
            float t = acc[b];
            t = fmaf(xa.x, wr[0], t); t = fmaf(xa.y, wr[1], t);
            t = fmaf(xa.z, wr[2], t); t = fmaf(xa.w, wr[3], t);
            t = fmaf(xb.x, wr[4], t); t = fmaf(xb.y, wr[5], t);
            t = fmaf(xb.z, wr[6], t); t = fmaf(xb.w, wr[7], t);
            acc[b] = t;
        }
    }
#pragma unroll
    for (int b = 0; b < BB; ++b)
        part[(size_t)blockIdx.y * (BB * DIM) + (size_t)b * DIM + j] = acc[b];
}

extern "C" void kernel_launch(void* const* d_in, const int* in_sizes, int n_in,
                              void* d_out, int out_size, void* d_ws, size_t ws_size,
                              hipStream_t stream) {
    const float* x    = (const float*)d_in[0];
    const float* wqkv = (const float*)d_in[1];
    const float* wo   = (const float*)d_in[2];
    const float* rot  = (const float*)d_in[3];
    const float* ck   = (const float*)d_in[4];   // read-only (no cache mutation)
    const float* cv   = (const float*)d_in[5];
    const float* mask = (const float*)d_in[6];
    const int* curpos = (const int*)d_in[7];
    float* out        = (float*)d_out;

    char* ws = (char*)d_ws;
    float*  xqkv_part = (float*)(ws);                   // 25,165,824
    float*  xqkv      = (float*)(ws + 25165824);        // 786,432
    float*  qws       = (float*)(ws + 25952256);        // 524,288
    float*  kws       = (float*)(ws + 26476544);        // 131,072
    float*  opart     = (float*)(ws + 26607616);        // 2*256*4*128*4 = 1,048,576
    float2* stats     = (float2*)(ws + 28704768);       // 1024*2*8 = 16,384
    float*  attn      = (float*)(ws + 28737536);        // 524,288
    float*  out_part  = (float*)(ws + 29261824);        // 16,777,216
    // total ws used ~46 MB

    k_qkv  <<<dim3(QKVC / 256, QKV_SPLITS), 256, 0, stream>>>(x, wqkv, xqkv_part);
    k_red  <<<dim3(192),                    256, 0, stream>>>(xqkv_part, xqkv, QKV_SPLITS, BB * QKVC / 4);
    k_rot  <<<dim3(40, BB),                 128, 0, stream>>>(xqkv, rot, qws, kws);
    k_attn <<<dim3(BB * NKV, ASPLIT),       512, 0, stream>>>(ck, cv, qws, kws, xqkv, mask, curpos, opart, stats);
    k_merge<<<dim3(BB * NKV),               128, 0, stream>>>(opart, stats, attn);
    k_wo   <<<dim3(DIM / 256, WO_SPLITS),   256, 0, stream>>>(attn, wo, out_part);
    k_red  <<<dim3(128),                    256, 0, stream>>>(out_part, out, WO_SPLITS, BB * DIM / 4);
}

// Round 10
// 1289.931 us; speedup vs baseline: 1.1478x; 1.1478x over previous
//
#include <hip/hip_runtime.h>

#define BB 32
#define DIM 4096
#define NH 32
#define NKV 8
#define HD 128
#define KVLEN 4096
#define QKVC 6144  // DIM + 2*NKV*HD
#define GQ 4
#define QKV_SPLITS 32
#define WO_SPLITS 32
#define ASPLIT 2   // KV splits for k_attn (2048 keys each) -> 512 blocks, ALL resident
#define NT 32      // tiles per block (2048 / 64)

typedef const __attribute__((address_space(1))) char gas_char;
typedef __attribute__((address_space(3))) char las_char;
#define GLL16(GP, LP) __builtin_amdgcn_global_load_lds((gas_char*)(GP), (las_char*)(LP), 16, 0, 0)

// ---------------- kernel A: xqkv partials = x @ wqkv (K-split, partials) -------
// 16-deep weight pipeline: 16x256B per wave in flight (~60 VGPR, no spill).
__global__ __launch_bounds__(256, 4) void k_qkv(const float* __restrict__ x,
                                                const float* __restrict__ w,
                                                float* __restrict__ part) {
    int j  = blockIdx.x * 256 + threadIdx.x;          // column 0..6143 (24 blocks)
    int d0 = blockIdx.y * (DIM / QKV_SPLITS);         // 128 rows per split
    float acc[BB];
#pragma unroll
    for (int b = 0; b < BB; ++b) acc[b] = 0.f;
    for (int dd = d0; dd < d0 + DIM / QKV_SPLITS; dd += 16) {
        float wr[16];
#pragma unroll
        for (int k = 0; k < 16; ++k) wr[k] = w[(size_t)(dd + k) * QKVC + j];
#pragma unroll
        for (int b = 0; b < BB; ++b) {
            float4 xa = *(const float4*)&x[b * DIM + dd];      // wave-uniform
            float4 xb = *(const float4*)&x[b * DIM + dd + 4];
            float4 xc = *(const float4*)&x[b * DIM + dd + 8];
            float4 xd = *(const float4*)&x[b * DIM + dd + 12];
            float t = acc[b];
            t = fmaf(xa.x, wr[0],  t); t = fmaf(xa.y, wr[1],  t);
            t = fmaf(xa.z, wr[2],  t); t = fmaf(xa.w, wr[3],  t);
            t = fmaf(xb.x, wr[4],  t); t = fmaf(xb.y, wr[5],  t);
            t = fmaf(xb.z, wr[6],  t); t = fmaf(xb.w, wr[7],  t);
            t = fmaf(xc.x, wr[8],  t); t = fmaf(xc.y, wr[9],  t);
            t = fmaf(xc.z, wr[10], t); t = fmaf(xc.w, wr[11], t);
            t = fmaf(xd.x, wr[12], t); t = fmaf(xd.y, wr[13], t);
            t = fmaf(xd.z, wr[14], t); t = fmaf(xd.w, wr[15], t);
            acc[b] = t;
        }
    }
#pragma unroll
    for (int b = 0; b < BB; ++b)
        part[(size_t)blockIdx.y * (BB * QKVC) + (size_t)b * QKVC + j] = acc[b];
}

// ---------------- generic split reduction: dst = sum_p src[p] ------------------
__global__ __launch_bounds__(256) void k_red(const float* __restrict__ src,
                                             float* __restrict__ dst,
                                             int parts, int n4) {
    int i = blockIdx.x * 256 + threadIdx.x;
    if (i >= n4) return;
    const float4* s4 = (const float4*)src;
    float4 a = s4[i];
    for (int p = 1; p < parts; ++p) {
        float4 b = s4[(size_t)p * n4 + i];
        a.x += b.x; a.y += b.y; a.z += b.z; a.w += b.w;
    }
    ((float4*)dst)[i] = a;
}

// ---------------- kernel R: rotary for q,k -> scratch (NO cache writes) --------
__global__ __launch_bounds__(128) void k_rot(const float* __restrict__ xqkv,
                                             const float* __restrict__ rot,
                                             float* __restrict__ qws,
                                             float* __restrict__ kws) {
    int c  = blockIdx.x;    // 0..39: 0-31 q heads, 32-39 k heads
    int b  = blockIdx.y;    // batch
    int dp = threadIdx.x;   // 0..127 output dim
    const float* row = &xqkv[(size_t)b * QKVC + c * HD];
    float acc = 0.f;
#pragma unroll 4
    for (int d = 0; d < HD; ++d) acc = fmaf(row[d], rot[d * HD + dp], acc);
    if (c < 32) {
        qws[((size_t)b * NH + c) * HD + dp] = acc;
    } else {
        int kvh = c - 32;
        kws[((size_t)b * NKV + kvh) * HD + dp] = acc;
    }
}

// ---------------- kernel B: flash attention, single-barrier pipeline -----------
// r8 schedule with phase B pipelined ONE TILE BEHIND phase A: pl/rs parity
// double-buffered, so each iteration needs only ONE barrier (the next
// iteration's barrier is the producer->consumer fence). Staging issued AFTER
// the barrier (no buffer race: parity (t+1)&1 was last read by phaseA(t-1),
// which finished before this barrier). Uniform counted vmcnt(8); compiler
// auto-waits the V regs inside phase B. 4-acc ILP in the QK dot.
__global__ __launch_bounds__(256) void k_attn(const float* __restrict__ ck,
                                              const float* __restrict__ cv,
                                              const float* __restrict__ qws,
                                              const float* __restrict__ kws,
                                              const float* __restrict__ xqkv,
                                              const float* __restrict__ mask,
                                              const int* __restrict__ curpos,
                                              float* __restrict__ opart,
                                              float2* __restrict__ stats) {
    __shared__ float Kl[2][64 * 128];   // 64 KB, linear (gll dest), XOR-swizzled
    __shared__ float mbuf[2][GQ * 64];  // 2 KB mask tiles
    __shared__ float ql[GQ][HD];        // 2 KB
    __shared__ float pl[2][GQ * 64];    // 2 KB probabilities (parity dbuf)
    __shared__ float rs[2][GQ];         // rescale factors (parity dbuf)
    int bkv = blockIdx.x;               // 0..255
    int split = blockIdx.y;             // 0..1
    int b = bkv >> 3, kv = bkv & 7;
    int tid = threadIdx.x;
    int wv = tid >> 6, lane = tid & 63;    // phase A: wave = head
    int d4 = tid & 31, sub = tid >> 5;     // phase B: 8 subs x 8 keys
    int lrh = lane >> 5;                   // row half for staging
    int sbyte = (lane & 31) << 4;          // swizzle byte offset
    int pos = *curpos;
    int L = min((((pos + 1) + 31) >> 5) << 5, KVLEN);
    int l0 = split * (NT * 64);
    int h = kv * GQ + wv;
    const float scale = 0.08838834764831845f;  // 1/sqrt(128)

    // q of own head -> LDS (wave-local)
    *(float2*)&ql[wv][lane * 2] = *(const float2*)&qws[((size_t)b * NH + h) * HD + lane * 2];

    // dot(q[h], k_new) for the `pos` row (broadcast loads, once per block)
    float posdot;
    {
        const float4* kwr = (const float4*)&kws[((size_t)b * NKV + kv) * HD];
        const float4* qr  = (const float4*)&qws[((size_t)b * NH + h) * HD];
        float p0 = 0.f, p1 = 0.f, p2 = 0.f, p3 = 0.f;
#pragma unroll
        for (int i = 0; i < 32; i += 4) {
            float4 a0 = kwr[i],     c0 = qr[i];
            float4 a1 = kwr[i + 1], c1 = qr[i + 1];
            float4 a2 = kwr[i + 2], c2 = qr[i + 2];
            float4 a3 = kwr[i + 3], c3 = qr[i + 3];
            p0 += a0.x * c0.x + a0.y * c0.y + a0.z * c0.z + a0.w * c0.w;
            p1 += a1.x * c1.x + a1.y * c1.y + a1.z * c1.z + a1.w * c1.w;
            p2 += a2.x * c2.x + a2.y * c2.y + a2.z * c2.z + a2.w * c2.w;
            p3 += a3.x * c3.x + a3.y * c3.y + a3.z * c3.z + a3.w * c3.w;
        }
        posdot = (p0 + p1) + (p2 + p3);
    }
    float4 vnew4 = *(const float4*)&xqkv[(size_t)b * QKVC + (size_t)(NH + NKV) * HD + kv * HD + d4 * 4];

    const char*   Ktile0 = (const char*)(ck + ((size_t)bkv * KVLEN + l0) * HD);
    const float4* Vt0    = (const float4*)(cv + ((size_t)bkv * KVLEN + l0) * HD);

#define STAGE_K(T, BUFI) do {                                                    \
        const char* kb_ = Ktile0 + (size_t)(T) * 32768;                          \
        _Pragma("unroll")                                                        \
        for (int i_ = 0; i_ < 8; ++i_) {                                         \
            int row_ = (i_ * 4 + wv) * 2 + lrh;                                  \
            int col_ = sbyte ^ ((row_ & 31) << 4);                               \
            GLL16(kb_ + (size_t)row_ * 512 + col_, &Kl[BUFI][(i_ * 4 + wv) * 256]); \
        }                                                                        \
    } while (0)

#define STAGE_M(T, BUFI) do {                                                    \
        int hh_ = lane >> 4, kk_ = lane & 15;                                    \
        const float* mg_ = mask + (((size_t)(kv * GQ + hh_) * BB + b) * KVLEN    \
                                   + l0 + (T) * 64 + kk_ * 4);                   \
        GLL16(mg_, &mbuf[BUFI][0]);                                              \
    } while (0)

#define LOADV(T, VBUF) do {                                                      \
        _Pragma("unroll")                                                        \
        for (int i_ = 0; i_ < 8; ++i_)                                           \
            (VBUF)[i_] = Vt0[(size_t)((T) * 64 + sub * 8 + i_) * 32 + d4];       \
    } while (0)

    float m = -3.0e38f, lsum = 0.f;
    float4 acc[GQ];
#pragma unroll
    for (int gg = 0; gg < GQ; ++gg) acc[gg] = make_float4(0.f, 0.f, 0.f, 0.f);
    float4 vA[8], vB[8];

// phase A for tile T (writes pl[(T)&1], rs[(T)&1])
#define PHASE_A(T) do {                                                          \
        int par_ = (T) & 1;                                                      \
        int lk_ = l0 + (T) * 64 + lane;                                          \
        const char* klr_ = (const char*)&Kl[par_][0] + lane * 512;               \
        float s0_ = 0.f, s1_ = 0.f, s2_ = 0.f, s3_ = 0.f;                        \
        _Pragma("unroll")                                                        \
        for (int dd_ = 0; dd_ < 32; dd_ += 4) {                                  \
            float4 k0_ = *(const float4*)(klr_ + (((dd_ + 0) * 16) ^ sbyte));    \
            float4 q0_ = *(const float4*)&ql[wv][(dd_ + 0) * 4];                 \
            float4 k1_ = *(const float4*)(klr_ + (((dd_ + 1) * 16) ^ sbyte));    \
            float4 q1_ = *(const float4*)&ql[wv][(dd_ + 1) * 4];                 \
            float4 k2_ = *(const float4*)(klr_ + (((dd_ + 2) * 16) ^ sbyte));    \
            float4 q2_ = *(const float4*)&ql[wv][(dd_ + 2) * 4];                 \
            float4 k3_ = *(const float4*)(klr_ + (((dd_ + 3) * 16) ^ sbyte));    \
            float4 q3_ = *(const float4*)&ql[wv][(dd_ + 3) * 4];                 \
            s0_ += k0_.x * q0_.x + k0_.y * q0_.y + k0_.z * q0_.z + k0_.w * q0_.w; \
            s1_ += k1_.x * q1_.x + k1_.y * q1_.y + k1_.z * q1_.z + k1_.w * q1_.w; \
            s2_ += k2_.x * q2_.x + k2_.y * q2_.y + k2_.z * q2_.z + k2_.w * q2_.w; \
            s3_ += k3_.x * q3_.x + k3_.y * q3_.y + k3_.z * q3_.z + k3_.w * q3_.w; \
        }                                                                        \
        float sdot_ = (s0_ + s1_) + (s2_ + s3_);                                 \
        if (lk_ == pos) sdot_ = posdot;                                          \
        float s_ = sdot_ * scale + mbuf[par_][wv * 64 + lane];                   \
        if (lk_ >= L) s_ = -3.0e38f;                                             \
        float smax_ = s_;                                                        \
        _Pragma("unroll")                                                        \
        for (int off_ = 32; off_ > 0; off_ >>= 1)                                \
            smax_ = fmaxf(smax_, __shfl_xor(smax_, off_));                       \
        float mnew_ = fmaxf(m, smax_);                                           \
        float r_ = __expf(m - mnew_);                                            \
        float e_ = (lk_ < L) ? __expf(s_ - mnew_) : 0.f;                         \
        float esum_ = e_;                                                        \
        _Pragma("unroll")                                                        \
        for (int off_ = 32; off_ > 0; off_ >>= 1)                                \
            esum_ += __shfl_xor(esum_, off_);                                    \
        lsum = lsum * r_ + esum_;                                                \
        m = mnew_;                                                               \
        pl[par_][wv * 64 + lane] = e_;                                           \
        if (lane == 0) rs[par_][wv] = r_;                                        \
    } while (0)

// phase B for tile TB (reads pl[(TB)&1], rs[(TB)&1], V regs VC of tile TB)
#define PHASE_B(TB, VC) do {                                                     \
        int parb_ = (TB) & 1;                                                    \
        int prow_ = pos - (l0 + (TB) * 64);                                      \
        _Pragma("unroll")                                                        \
        for (int gg_ = 0; gg_ < GQ; ++gg_) {                                     \
            float rg_ = rs[parb_][gg_];                                          \
            acc[gg_].x *= rg_; acc[gg_].y *= rg_;                                \
            acc[gg_].z *= rg_; acc[gg_].w *= rg_;                                \
        }                                                                        \
        _Pragma("unroll")                                                        \
        for (int i_ = 0; i_ < 8; ++i_) {                                         \
            float4 v_ = (sub * 8 + i_ == prow_) ? vnew4 : (VC)[i_];              \
            _Pragma("unroll")                                                    \
            for (int gg_ = 0; gg_ < GQ; ++gg_) {                                 \
                float p_ = pl[parb_][gg_ * 64 + sub * 8 + i_];                   \
                acc[gg_].x = fmaf(p_, v_.x, acc[gg_].x);                         \
                acc[gg_].y = fmaf(p_, v_.y, acc[gg_].y);                         \
                acc[gg_].z = fmaf(p_, v_.z, acc[gg_].z);                         \
                acc[gg_].w = fmaf(p_, v_.w, acc[gg_].w);                         \
            }                                                                    \
        }                                                                        \
    } while (0)

// main tile: ONE barrier. V(T) loaded into VN (consumed next iter as tile T).
#define TILE(T, VC, VN) do {                                                     \
        asm volatile("s_waitcnt vmcnt(8)" ::: "memory");                         \
        asm volatile("s_waitcnt lgkmcnt(0)" ::: "memory");                       \
        __builtin_amdgcn_s_barrier();                                            \
        if ((T) < NT - 1) {                                                      \
            STAGE_K((T) + 1, ((T) + 1) & 1);                                     \
            if (wv == 0) STAGE_M((T) + 1, ((T) + 1) & 1);                        \
        }                                                                        \
        LOADV(T, VN);                                                            \
        PHASE_A(T);                                                              \
        PHASE_B((T) - 1, VC);                                                    \
    } while (0)

    // prologue: K(0)/M(0) in flight
    STAGE_K(0, 0);
    if (wv == 0) STAGE_M(0, 0);

    // peeled iteration 0 (no phase B yet)
    asm volatile("s_waitcnt vmcnt(0)" ::: "memory");
    asm volatile("s_waitcnt lgkmcnt(0)" ::: "memory");
    __builtin_amdgcn_s_barrier();
    STAGE_K(1, 1);
    if (wv == 0) STAGE_M(1, 1);
    LOADV(0, vA);
    PHASE_A(0);

    // V(t) parity: t even -> vA, t odd -> vB; consume V(t-1)
    for (int tt = 1; tt < NT - 1; tt += 2) {
        TILE(tt,     vA, vB);   // consumes V(tt-1)=vA, loads V(tt)->vB
        TILE(tt + 1, vB, vA);
    }
    TILE(NT - 1, vA, vB);       // consumes V(30)=vA, loads V(31)->vB

    if (lane == 0) stats[(bkv * GQ + wv) * ASPLIT + split] = make_float2(m, lsum);

    // epilogue: phase B for the last tile
    asm volatile("s_waitcnt lgkmcnt(0)" ::: "memory");
    __builtin_amdgcn_s_barrier();
    PHASE_B(NT - 1, vB);

    // cross-sub reduce of O partials (alias Kl as scratch; pipeline done)
    __syncthreads();
    float* red = &Kl[0][0];   // 8*4*128 floats = 16 KB
#pragma unroll
    for (int gg = 0; gg < GQ; ++gg)
        *(float4*)&red[(sub * GQ + gg) * HD + d4 * 4] = acc[gg];
    __syncthreads();
#pragma unroll
    for (int rep = 0; rep < 2; ++rep) {
        int idx = rep * 256 + tid;         // 0..511 = (g,d)
        int g2 = idx >> 7, d = idx & 127;
        float o = 0.f;
#pragma unroll
        for (int k = 0; k < 8; ++k) o += red[(k * GQ + g2) * HD + d];
        opart[(((size_t)split * 256 + bkv) * GQ + g2) * HD + d] = o;
    }
#undef TILE
#undef PHASE_A
#undef PHASE_B
#undef LOADV
#undef STAGE_K
#undef STAGE_M
}

// ---------------- kernel M: merge ASPLIT split partials -> attn ----------------
__global__ __launch_bounds__(128) void k_merge(const float* __restrict__ opart,
                                               const float2* __restrict__ stats,
                                               float* __restrict__ attn) {
    int bkv = blockIdx.x;    // 0..255
    int d = threadIdx.x;     // 0..127
    int b = bkv >> 3, kv = bkv & 7;
#pragma unroll
    for (int g = 0; g < GQ; ++g) {
        float2 st[ASPLIT];
        float M = -3.0e38f;
#pragma unroll
        for (int s = 0; s < ASPLIT; ++s) {
            st[s] = stats[(bkv * GQ + g) * ASPLIT + s];
            M = fmaxf(M, st[s].x);
        }
        float Ltot = 0.f;
        float w[ASPLIT];
#pragma unroll
        for (int s = 0; s < ASPLIT; ++s) {
            w[s] = __expf(st[s].x - M);
            Ltot += st[s].y * w[s];
        }
        float inv = Ltot > 0.f ? 1.f / Ltot : 0.f;
        float o = 0.f;
#pragma unroll
        for (int s = 0; s < ASPLIT; ++s)
            o += opart[(((size_t)s * 256 + bkv) * GQ + g) * HD + d] * (w[s] * inv);
        attn[(size_t)b * DIM + (kv * GQ + g) * HD + d] = o;
    }
}

// ---------------- kernel C: out partials = attn @ wo (K-split, partials) -------
__global__ __launch_bounds__(256, 4) void k_wo(const float* __restrict__ attn,
                                               const float* __restrict__ wo,
                                               float* __restrict__ part) {
    int j  = blockIdx.x * 256 + threadIdx.x;       // 0..4095 (16 blocks)
    int d0 = blockIdx.y * (DIM / WO_SPLITS);       // 128 rows per split
    float acc[BB];
#pragma unroll
    for (int b = 0; b < BB; ++b) acc[b] = 0.f;
    for (int dd = d0; dd < d0 + DIM / WO_SPLITS; dd += 8) {
        float wr[8];
#pragma unroll
        for (int k = 0; k < 8; ++k) wr[k] = wo[(size_t)(dd + k) * DIM + j];
#pragma unroll
        for (int b = 0; b < BB; ++b) {
            float4 xa = *(const float4*)&attn[b * DIM + dd];   // wave-uniform
            float4 xb = *(const float4*)&attn[b * DIM + dd + 4];
            float t = acc[b];
            t = fmaf(xa.x, wr[0], t); t = fmaf(xa.y, wr[1], t);
            t = fmaf(xa.z, wr[2], t); t = fmaf(xa.w, wr[3], t);
            t = fmaf(xb.x, wr[4], t); t = fmaf(xb.y, wr[5], t);
            t = fmaf(xb.z, wr[6], t); t = fmaf(xb.w, wr[7], t);
            acc[b] = t;
        }
    }
#pragma unroll
    for (int b = 0; b < BB; ++b)
        part[(size_t)blockIdx.y * (BB * DIM) + (size_t)b * DIM + j] = acc[b];
}

extern "C" void kernel_launch(void* const* d_in, const int* in_sizes, int n_in,
                              void* d_out, int out_size, void* d_ws, size_t ws_size,
                              hipStream_t stream) {
    const float* x    = (const float*)d_in[0];
    const float* wqkv = (const float*)d_in[1];
    const float* wo   = (const float*)d_in[2];
    const float* rot  = (const float*)d_in[3];
    const float* ck   = (const float*)d_in[4];   // read-only (no cache mutation)
    const float* cv   = (const float*)d_in[5];
    const float* mask = (const float*)d_in[6];
    const int* curpos = (const int*)d_in[7];
    float* out        = (float*)d_out;

    char* ws = (char*)d_ws;
    float*  xqkv_part = (float*)(ws);                   // 25,165,824
    float*  xqkv      = (float*)(ws + 25165824);        // 786,432
    float*  qws       = (float*)(ws + 25952256);        // 524,288
    float*  kws       = (float*)(ws + 26476544);        // 131,072
    float*  opart     = (float*)(ws + 26607616);        // 2*256*4*128*4 = 1,048,576
    float2* stats     = (float2*)(ws + 28704768);       // 1024*2*8 = 16,384
    float*  attn      = (float*)(ws + 28737536);        // 524,288
    float*  out_part  = (float*)(ws + 29261824);        // 16,777,216
    // total ws used ~46 MB

    k_qkv  <<<dim3(QKVC / 256, QKV_SPLITS), 256, 0, stream>>>(x, wqkv, xqkv_part);
    k_red  <<<dim3(192),                    256, 0, stream>>>(xqkv_part, xqkv, QKV_SPLITS, BB * QKVC / 4);
    k_rot  <<<dim3(40, BB),                 128, 0, stream>>>(xqkv, rot, qws, kws);
    k_attn <<<dim3(BB * NKV, ASPLIT),       256, 0, stream>>>(ck, cv, qws, kws, xqkv, mask, curpos, opart, stats);
    k_merge<<<dim3(BB * NKV),               128, 0, stream>>>(opart, stats, attn);
    k_wo   <<<dim3(DIM / 256, WO_SPLITS),   256, 0, stream>>>(attn, wo, out_part);
    k_red  <<<dim3(128),                    256, 0, stream>>>(out_part, out, WO_SPLITS, BB * DIM / 4);
}